// Round 1
// baseline (6488.926 us; speedup 1.0000x reference)
//
#include <hip/hip_runtime.h>
#include <hip/hip_bf16.h>

typedef unsigned short u16;
typedef __attribute__((ext_vector_type(8))) short bf16x8;
typedef __attribute__((ext_vector_type(4))) float f32x4;
typedef __attribute__((ext_vector_type(4))) unsigned short u16x4;

#define MFMA_B16(a,b,c) __builtin_amdgcn_mfma_f32_16x16x32_bf16((a),(b),(c),0,0,0)

// sizes
#define BB 128
#define TT 512
#define HH 256
#define DIN 102

__device__ __forceinline__ u16 f2bf(float f){
  unsigned u = __float_as_uint(f);
  u += 0x7fffu + ((u >> 16) & 1u);          // RNE; inputs are finite
  return (u16)(u >> 16);
}
__device__ __forceinline__ float bf2f(u16 v){ return __uint_as_float(((unsigned)v) << 16); }
__device__ __forceinline__ float sigm(float x){ return 1.f/(1.f + __expf(-x)); }
__device__ __forceinline__ float tanh_f(float x){ return 1.f - 2.f/(__expf(2.f*x) + 1.f); }

// ---------------- pack kernels ----------------
__global__ __launch_bounds__(256) void pack_x(const float* __restrict__ x, u16* __restrict__ xT){
  int idx = blockIdx.x*256 + threadIdx.x;          // [t][b][c128]
  int c = idx & 127, b = (idx >> 7) & 127, t = idx >> 14;
  float v = (c < DIN) ? x[((size_t)b*TT + t)*DIN + c] : 0.f;
  xT[idx] = f2bf(v);
}
__global__ __launch_bounds__(256) void pack_whh(const float* __restrict__ wf, const float* __restrict__ wb,
                                                u16* __restrict__ dst){
  int idx = blockIdx.x*256 + threadIdx.x;          // [d][1024][256]
  int d = idx >> 18; int s = idx & 0x3FFFF;
  dst[idx] = f2bf((d ? wb : wf)[s]);
}
__global__ __launch_bounds__(256) void pack_wih(const float* __restrict__ wf, const float* __restrict__ wb,
                                                u16* __restrict__ dst){
  int idx = blockIdx.x*256 + threadIdx.x;          // [d][1024][128] padded from 102
  int d = idx >> 17; int r = (idx >> 7) & 1023; int k = idx & 127;
  float v = (k < DIN) ? (d ? wb : wf)[r*DIN + k] : 0.f;
  dst[idx] = f2bf(v);
}
__global__ __launch_bounds__(256) void pack_wlin(const float* __restrict__ w, u16* __restrict__ dst){
  int idx = blockIdx.x*256 + threadIdx.x;          // [128][512]
  dst[idx] = f2bf(w[idx]);
}

// ---------------- persistent BiLSTM scan ----------------
// grid 256 = 2 dirs x 8 batch-tiles(16) x 16 h-slices(16); block 256 (4 waves)
// wave wv handles k-chunks {2wv,2wv+1} of Whh (K=256) and chunk wv of Wih (K=128),
// for all 4 gate groups; partial gates reduced via LDS.
__global__ __launch_bounds__(256, 1) void lstm_scan(
    const u16* __restrict__ xT, const u16* __restrict__ Whh,
    const u16* __restrict__ Wih, const float* __restrict__ b_f,
    const float* __restrict__ b_b, u16* __restrict__ Hst,
    int* __restrict__ flags)
{
  const int w  = blockIdx.x;
  const int hs = w >> 4;                 // h-slice in HIGH bits -> sync-group members share blockIdx%8 (XCD)
  const int d  = (w >> 3) & 1;
  const int bt = w & 7;
  const int tid = threadIdx.x;
  const int wv = tid >> 6, lane = tid & 63;
  const int r16 = lane & 15, kq = lane >> 4;

  __shared__ float gacc[4][4][16][17];   // [wave][gate][b_local][j_local] padded

  // weight fragments in registers (held across whole time loop)
  bf16x8 wfh[4][2], wfi[4];
  const float* bias = d ? b_b : b_f;
  float bias_r[4];
  #pragma unroll
  for (int g = 0; g < 4; ++g) {
    int row = g*256 + hs*16 + r16;
    const u16* ph = Whh + ((size_t)d*1024 + row)*256 + wv*64 + kq*8;
    wfh[g][0] = *(const bf16x8*)ph;
    wfh[g][1] = *(const bf16x8*)(ph + 32);
    const u16* pi = Wih + ((size_t)d*1024 + row)*128 + wv*32 + kq*8;
    wfi[g] = *(const bf16x8*)pi;
    bias_r[g] = (wv == 0) ? bias[row] : 0.f;   // bias added exactly once across waves
  }

  const int pb = tid >> 4, pj = tid & 15;          // pointwise ownership
  const int bglob = bt*16 + pb, jglob = hs*16 + pj;
  const int btb = bt*16;
  float c_state = 0.f;

  for (int s = 0; s < TT; ++s) {
    const int t = d ? (TT-1 - s) : s;
    const int tprev = d ? (t + 1) : (t - 1);

    f32x4 acc[4];
    #pragma unroll
    for (int g = 0; g < 4; ++g) acc[g] = (f32x4){bias_r[g],bias_r[g],bias_r[g],bias_r[g]};

    bf16x8 xa, ha0, ha1;
    if (s > 0) {
      const int fo = ((d*TT + tprev)*8 + bt) * 16;
      if (tid == 0) {
        while (__hip_atomic_load(&flags[fo], __ATOMIC_RELAXED, __HIP_MEMORY_SCOPE_AGENT) < 16) { }
      }
      __syncthreads();
      __builtin_amdgcn_fence(__ATOMIC_ACQUIRE, "agent");
      const u16* hp = Hst + (((size_t)d*TT + tprev)*BB + btb + r16)*256 + wv*64 + kq*8;
      ha0 = *(const bf16x8*)hp;
      ha1 = *(const bf16x8*)(hp + 32);
      const u16* xp = xT + ((size_t)t*BB + btb + r16)*128 + wv*32 + kq*8;
      xa = *(const bf16x8*)xp;
      #pragma unroll
      for (int g = 0; g < 4; ++g) {
        acc[g] = MFMA_B16(xa,  wfi[g],    acc[g]);
        acc[g] = MFMA_B16(ha0, wfh[g][0], acc[g]);
        acc[g] = MFMA_B16(ha1, wfh[g][1], acc[g]);
      }
    } else {
      const u16* xp = xT + ((size_t)t*BB + btb + r16)*128 + wv*32 + kq*8;
      xa = *(const bf16x8*)xp;
      #pragma unroll
      for (int g = 0; g < 4; ++g) acc[g] = MFMA_B16(xa, wfi[g], acc[g]);
    }

    // D layout: row(b_local) = kq*4+rr, col(j_local) = r16  [m89-verified]
    #pragma unroll
    for (int g = 0; g < 4; ++g)
      #pragma unroll
      for (int rr = 0; rr < 4; ++rr)
        gacc[wv][g][kq*4 + rr][r16] = acc[g][rr];
    __syncthreads();

    float iv = 0.f, fv = 0.f, gv = 0.f, ov = 0.f;
    #pragma unroll
    for (int u = 0; u < 4; ++u) {
      iv += gacc[u][0][pb][pj];
      fv += gacc[u][1][pb][pj];
      gv += gacc[u][2][pb][pj];
      ov += gacc[u][3][pb][pj];
    }
    float ig = sigm(iv), fg = sigm(fv), gg = tanh_f(gv), og = sigm(ov);
    c_state = fg*c_state + ig*gg;
    float h = og * tanh_f(c_state);
    Hst[(((size_t)d*TT + t)*BB + bglob)*256 + jglob] = f2bf(h);
    __syncthreads();                                 // drains all stores (vmcnt0) before flag
    if (tid == 0)
      __hip_atomic_fetch_add(&flags[((d*TT + t)*8 + bt) * 16], 1,
                             __ATOMIC_RELEASE, __HIP_MEMORY_SCOPE_AGENT);
  }
}

// ---------------- linear (512->128) + ELU ----------------
// grid 512 (one t per WG); feats = [H_fwd | H_bwd] read straight from Hst.
__global__ __launch_bounds__(256) void linear_elu(
    const u16* __restrict__ Hst, const u16* __restrict__ Wlin_pk,
    const float* __restrict__ blin, u16* __restrict__ feats2)
{
  const int t = blockIdx.x;
  const int tid = threadIdx.x;
  const int wv = tid >> 6, lane = tid & 63;
  const int r16 = lane & 15, kq = lane >> 4;
  __shared__ u16 w1s[32*512];   // 32KB quarter of W1, XOR-swizzled rows

  f32x4 acc[2][8];
  #pragma unroll
  for (int mi = 0; mi < 2; ++mi)
    #pragma unroll
    for (int nt = 0; nt < 8; ++nt) {
      float bv = blin[nt*16 + r16];
      acc[mi][nt] = (f32x4){bv,bv,bv,bv};
    }

  #pragma unroll
  for (int q = 0; q < 4; ++q) {
    __syncthreads();
    for (int i = tid; i < 2048; i += 256) {        // 32 rows x 64 chunks of 8 elems
      int rl = i >> 6, ch = i & 63;
      int dst = rl*1024 + ((ch*16) ^ ((rl & 7) << 4));
      *(bf16x8*)((char*)w1s + dst) = *(const bf16x8*)(Wlin_pk + (size_t)(q*32 + rl)*512 + ch*8);
    }
    __syncthreads();
    #pragma unroll
    for (int mi = 0; mi < 2; ++mi) {
      const int mb = (wv*2 + mi)*16;
      #pragma unroll
      for (int kc = 0; kc < 16; ++kc) {
        const int dd = kc >> 3, ki = kc & 7;
        const u16* ap = Hst + (((size_t)dd*TT + t)*BB + mb + r16)*256 + ki*32 + kq*8;
        bf16x8 a = *(const bf16x8*)ap;
        #pragma unroll
        for (int ntl = 0; ntl < 2; ++ntl) {
          int rl = ntl*16 + r16;
          int boff = kc*64 + kq*16;
          const u16* bp = (const u16*)((const char*)w1s + rl*1024 + (boff ^ ((rl & 7) << 4)));
          acc[mi][q*2 + ntl] = MFMA_B16(a, *(const bf16x8*)bp, acc[mi][q*2 + ntl]);
        }
      }
    }
  }
  // epilogue: ELU, pack 4 consecutive b, store feats2[t][n][b]
  #pragma unroll
  for (int mi = 0; mi < 2; ++mi) {
    const int mb = (wv*2 + mi)*16;
    #pragma unroll
    for (int nt = 0; nt < 8; ++nt) {
      u16x4 pk;
      #pragma unroll
      for (int rr = 0; rr < 4; ++rr) {
        float y = acc[mi][nt][rr];
        y = (y > 0.f) ? y : (__expf(y) - 1.f);
        pk[rr] = f2bf(y);
      }
      int n = nt*16 + r16;
      int bcol = mb + kq*4;
      *(u16x4*)(feats2 + ((size_t)t*128 + n)*BB + bcol) = pk;
    }
  }
}

// ---------------- classifier (128 -> 9) ----------------
__global__ __launch_bounds__(256) void cls_kernel(
    const u16* __restrict__ feats2, const float* __restrict__ Wcls,
    const float* __restrict__ bcls, float* __restrict__ em)
{
  __shared__ float w2s[9*128];
  __shared__ float b2s[9];
  const int tid = threadIdx.x;
  for (int i = tid; i < 9*128; i += 256) w2s[i] = Wcls[i];
  if (tid < 9) b2s[tid] = bcls[tid];
  __syncthreads();
  const int bb = tid & 127;
  const int t = blockIdx.x*2 + (tid >> 7);
  float accv[9];
  #pragma unroll
  for (int j = 0; j < 9; ++j) accv[j] = b2s[j];
  for (int n = 0; n < 128; ++n) {
    float y = bf2f(feats2[((size_t)t*128 + n)*BB + bb]);
    #pragma unroll
    for (int j = 0; j < 9; ++j) accv[j] = fmaf(w2s[j*128 + n], y, accv[j]);
  }
  #pragma unroll
  for (int j = 0; j < 9; ++j) em[((size_t)bb*TT + t)*9 + j] = accv[j];
}

// ---------------- CRF NLL per batch element ----------------
__global__ __launch_bounds__(64) void crf_kernel(
    const float* __restrict__ em, const int* __restrict__ labels,
    const float* __restrict__ start_t, const float* __restrict__ end_t,
    const float* __restrict__ trans, float* __restrict__ vals)
{
  const int b = blockIdx.x;
  const int lane = threadIdx.x;
  __shared__ float tr_s[81];
  for (int i = lane; i < 81; i += 64) tr_s[i] = trans[i];
  __syncthreads();
  const int* lb = labels + (size_t)b*TT;
  const float* emb = em + (size_t)b*TT*9;

  // numerator (mask is all ones, seq_len == T)
  float nsum = 0.f;
  for (int t = lane; t < TT; t += 64) {
    int lt = lb[t];
    float v = emb[t*9 + lt];
    v += (t == 0) ? start_t[lt] : tr_s[lb[t-1]*9 + lt];
    nsum += v;
  }
  #pragma unroll
  for (int o = 32; o > 0; o >>= 1) nsum += __shfl_down(nsum, o, 64);

  // forward algorithm; alpha replicated across lanes via shfl
  float tr_reg[9];
  #pragma unroll
  for (int i = 0; i < 9; ++i) tr_reg[i] = 0.f;
  if (lane < 9) {
    #pragma unroll
    for (int i = 0; i < 9; ++i) tr_reg[i] = tr_s[i*9 + lane];
  }
  float alpha_j = (lane < 9) ? (start_t[lane] + emb[lane]) : -1e30f;
  float a_all[9];
  #pragma unroll
  for (int i = 0; i < 9; ++i) a_all[i] = __shfl(alpha_j, i, 64);
  float em_c = (lane < 9) ? emb[9 + lane] : 0.f;
  for (int t = 1; t < TT; ++t) {
    float em_n = 0.f;
    if (t + 1 < TT && lane < 9) em_n = emb[(t+1)*9 + lane];   // prefetch
    float av[9];
    #pragma unroll
    for (int i = 0; i < 9; ++i) av[i] = a_all[i] + tr_reg[i];
    float m = av[0];
    #pragma unroll
    for (int i = 1; i < 9; ++i) m = fmaxf(m, av[i]);
    float ssum = 0.f;
    #pragma unroll
    for (int i = 0; i < 9; ++i) ssum += __expf(av[i] - m);
    float nxt = m + __logf(ssum) + em_c;
    #pragma unroll
    for (int i = 0; i < 9; ++i) a_all[i] = __shfl(nxt, i, 64);
    em_c = em_n;
  }
  if (lane == 0) {
    float vv[9];
    #pragma unroll
    for (int i = 0; i < 9; ++i) vv[i] = a_all[i] + end_t[i];
    float m = vv[0];
    #pragma unroll
    for (int i = 1; i < 9; ++i) m = fmaxf(m, vv[i]);
    float ssum = 0.f;
    #pragma unroll
    for (int i = 0; i < 9; ++i) ssum += __expf(vv[i] - m);
    float logZ = m + __logf(ssum);
    float num = nsum + end_t[lb[TT-1]];
    vals[b] = num - logZ;
  }
}

__global__ __launch_bounds__(128) void finalize_k(const float* __restrict__ vals, float* __restrict__ out){
  const int tid = threadIdx.x;
  float v = vals[tid];
  #pragma unroll
  for (int o = 32; o > 0; o >>= 1) v += __shfl_down(v, o, 64);
  __shared__ float sr[2];
  if ((tid & 63) == 0) sr[tid >> 6] = v;
  __syncthreads();
  if (tid == 0) out[0] = -(sr[0] + sr[1]);
}

// ---------------- launcher ----------------
extern "C" void kernel_launch(void* const* d_in, const int* in_sizes, int n_in,
                              void* d_out, int out_size, void* d_ws, size_t ws_size,
                              hipStream_t stream)
{
  const float* x       = (const float*)d_in[0];
  const int*   labels  = (const int*)d_in[2];
  const float* Wih_f   = (const float*)d_in[4];
  const float* Whh_f   = (const float*)d_in[5];
  const float* b_f     = (const float*)d_in[6];
  const float* Wih_b   = (const float*)d_in[7];
  const float* Whh_b   = (const float*)d_in[8];
  const float* b_b     = (const float*)d_in[9];
  const float* Wlin    = (const float*)d_in[10];
  const float* blin    = (const float*)d_in[11];
  const float* Wcls    = (const float*)d_in[12];
  const float* bcls    = (const float*)d_in[13];
  const float* start_t = (const float*)d_in[14];
  const float* end_t   = (const float*)d_in[15];
  const float* trans   = (const float*)d_in[16];

  char* p = (char*)d_ws;
  u16* xT     = (u16*)p;  p += (size_t)TT*BB*128*2;        // 16.78 MB
  u16* WhhP   = (u16*)p;  p += (size_t)2*1024*256*2;       //  1.05 MB
  u16* WihP   = (u16*)p;  p += (size_t)2*1024*128*2;       //  0.52 MB
  u16* WlinP  = (u16*)p;  p += (size_t)128*512*2;          //  0.13 MB
  u16* Hst    = (u16*)p;  p += (size_t)2*TT*BB*256*2;      // 67.1 MB
  u16* feats2 = (u16*)p;  p += (size_t)TT*128*BB*2;        // 16.78 MB
  float* em   = (float*)p; p += (size_t)BB*TT*9*4;         //  2.36 MB
  int* flags  = (int*)p;  p += (size_t)2*TT*8*16*4;        //  0.52 MB
  float* vals = (float*)p; p += 128*4;

  hipMemsetAsync(flags, 0, (size_t)2*TT*8*16*4, stream);
  pack_x   <<<32768, 256, 0, stream>>>(x, xT);
  pack_whh <<<2048,  256, 0, stream>>>(Whh_f, Whh_b, WhhP);
  pack_wih <<<1024,  256, 0, stream>>>(Wih_f, Wih_b, WihP);
  pack_wlin<<<256,   256, 0, stream>>>(Wlin, WlinP);
  lstm_scan<<<256,   256, 0, stream>>>(xT, WhhP, WihP, b_f, b_b, Hst, flags);
  linear_elu<<<512,  256, 0, stream>>>(Hst, WlinP, blin, feats2);
  cls_kernel<<<256,  256, 0, stream>>>(feats2, Wcls, bcls, em);
  crf_kernel<<<128,  64,  0, stream>>>(em, labels, start_t, end_t, trans, vals);
  finalize_k<<<1,    128, 0, stream>>>(vals, (float*)d_out);
}

// Round 2
// 1315.299 us; speedup vs baseline: 4.9334x; 4.9334x over previous
//
#include <hip/hip_runtime.h>
#include <hip/hip_bf16.h>

typedef unsigned short u16;
typedef unsigned int u32;
typedef unsigned long long u64;
typedef __attribute__((ext_vector_type(8))) short bf16x8;
typedef __attribute__((ext_vector_type(4))) float f32x4;
typedef __attribute__((ext_vector_type(4))) unsigned short u16x4;

#define MFMA_B16(a,b,c) __builtin_amdgcn_mfma_f32_16x16x32_bf16((a),(b),(c),0,0,0)

// sizes
#define BB 128
#define TT 512
#define HH 256
#define DIN 102

__device__ __forceinline__ u16 f2bf(float f){
  unsigned u = __float_as_uint(f);
  u += 0x7fffu + ((u >> 16) & 1u);          // RNE; inputs are finite
  return (u16)(u >> 16);
}
__device__ __forceinline__ float bf2f(u16 v){ return __uint_as_float(((unsigned)v) << 16); }
__device__ __forceinline__ float sigm(float x){ return 1.f/(1.f + __expf(-x)); }
__device__ __forceinline__ float tanh_f(float x){ return 1.f - 2.f/(__expf(2.f*x) + 1.f); }

// ---------------- pack kernels ----------------
__global__ __launch_bounds__(256) void pack_x(const float* __restrict__ x, u16* __restrict__ xT){
  int idx = blockIdx.x*256 + threadIdx.x;          // [t][b][c128]
  int c = idx & 127, b = (idx >> 7) & 127, t = idx >> 14;
  float v = (c < DIN) ? x[((size_t)b*TT + t)*DIN + c] : 0.f;
  xT[idx] = f2bf(v);
}
__global__ __launch_bounds__(256) void pack_whh(const float* __restrict__ wf, const float* __restrict__ wb,
                                                u16* __restrict__ dst){
  int idx = blockIdx.x*256 + threadIdx.x;          // [d][1024][256]
  int d = idx >> 18; int s = idx & 0x3FFFF;
  dst[idx] = f2bf((d ? wb : wf)[s]);
}
__global__ __launch_bounds__(256) void pack_wih(const float* __restrict__ wf, const float* __restrict__ wb,
                                                u16* __restrict__ dst){
  int idx = blockIdx.x*256 + threadIdx.x;          // [d][1024][128] padded from 102
  int d = idx >> 17; int r = (idx >> 7) & 1023; int k = idx & 127;
  float v = (k < DIN) ? (d ? wb : wf)[r*DIN + k] : 0.f;
  dst[idx] = f2bf(v);
}
__global__ __launch_bounds__(256) void pack_wlin(const float* __restrict__ w, u16* __restrict__ dst){
  int idx = blockIdx.x*256 + threadIdx.x;          // [128][512]
  dst[idx] = f2bf(w[idx]);
}

// ---------------- persistent BiLSTM scan ----------------
// grid 256 = 16 h-slices x 2 dirs x 8 batch-tiles; block 256 (4 waves).
// Cross-WG comm is ALL relaxed device-scope atomics (sc-bit path to the
// coherence point) -- zero acquire/release fences, so no buffer_inv/wbl2
// per step (that was the 12us/step killer in R1).
// Hst32: h packed 2xbf16 per u32, row = 128 u32 per (d,t,b).
// flags: one-shot per (d,t,bt,hs), stride 4 u32 (16B) to spread stores.
__global__ __launch_bounds__(256, 1) void lstm_scan(
    const u16* __restrict__ xT, const u16* __restrict__ Whh,
    const u16* __restrict__ Wih, const float* __restrict__ b_f,
    const float* __restrict__ b_b, u32* __restrict__ Hst32,
    u32* __restrict__ flags)
{
  const int w  = blockIdx.x;
  const int hs = w >> 4;                 // h-slice in HIGH bits (XCD heuristic only)
  const int d  = (w >> 3) & 1;
  const int bt = w & 7;
  const int tid = threadIdx.x;
  const int wv = tid >> 6, lane = tid & 63;
  const int r16 = lane & 15, kq = lane >> 4;

  __shared__ float gacc[4][4][16][17];   // [wave][gate][b_local][j_local] padded

  // weight fragments in registers (held across whole time loop)
  bf16x8 wfh[4][2], wfi[4];
  const float* bias = d ? b_b : b_f;
  float bias_r[4];
  #pragma unroll
  for (int g = 0; g < 4; ++g) {
    int row = g*256 + hs*16 + r16;
    const u16* ph = Whh + ((size_t)d*1024 + row)*256 + wv*64 + kq*8;
    wfh[g][0] = *(const bf16x8*)ph;
    wfh[g][1] = *(const bf16x8*)(ph + 32);
    const u16* pi = Wih + ((size_t)d*1024 + row)*128 + wv*32 + kq*8;
    wfi[g] = *(const bf16x8*)pi;
    bias_r[g] = (wv == 0) ? bias[row] : 0.f;   // bias added exactly once across waves
  }

  const int pb = tid >> 4, pj = tid & 15;          // pointwise ownership
  const int btb = bt*16;
  float c_state = 0.f;

  for (int s = 0; s < TT; ++s) {
    const int t = d ? (TT-1 - s) : s;
    const int tprev = d ? (t + 1) : (t - 1);

    f32x4 acc[4];
    #pragma unroll
    for (int g = 0; g < 4; ++g) acc[g] = (f32x4){bias_r[g],bias_r[g],bias_r[g],bias_r[g]};

    // x-part first: off the critical path, overlaps the wait below
    const u16* xp = xT + ((size_t)t*BB + btb + r16)*128 + wv*32 + kq*8;
    bf16x8 xa = *(const bf16x8*)xp;
    #pragma unroll
    for (int g = 0; g < 4; ++g) acc[g] = MFMA_B16(xa, wfi[g], acc[g]);

    if (s > 0) {
      // wave wv consumes k-dims [wv*64, wv*64+64) == slices 4wv..4wv+3.
      // Each wave polls ONLY its 4 flags and proceeds independently.
      const u32* fb = flags + ((size_t)((d*TT + tprev)*8 + bt))*64;
      if (lane < 4) {
        while (__hip_atomic_load(&fb[(wv*4 + lane)*4], __ATOMIC_RELAXED,
                                 __HIP_MEMORY_SCOPE_AGENT) == 0u) { }
      }
      asm volatile("" ::: "memory");   // no compiler reordering of data loads above poll

      const u64* hp = (const u64*)(Hst32 +
          (((size_t)d*TT + tprev)*BB + btb + r16)*128 + wv*32 + kq*4);
      u64 q0 = __hip_atomic_load(hp + 0, __ATOMIC_RELAXED, __HIP_MEMORY_SCOPE_AGENT);
      u64 q1 = __hip_atomic_load(hp + 1, __ATOMIC_RELAXED, __HIP_MEMORY_SCOPE_AGENT);
      u64 q2 = __hip_atomic_load(hp + 8, __ATOMIC_RELAXED, __HIP_MEMORY_SCOPE_AGENT);
      u64 q3 = __hip_atomic_load(hp + 9, __ATOMIC_RELAXED, __HIP_MEMORY_SCOPE_AGENT);
      union U { u64 q[2]; bf16x8 v; } u0, u1;
      u0.q[0] = q0; u0.q[1] = q1;
      u1.q[0] = q2; u1.q[1] = q3;
      bf16x8 ha0 = u0.v, ha1 = u1.v;
      #pragma unroll
      for (int g = 0; g < 4; ++g) {
        acc[g] = MFMA_B16(ha0, wfh[g][0], acc[g]);
        acc[g] = MFMA_B16(ha1, wfh[g][1], acc[g]);
      }
    }

    // D layout: row(b_local) = kq*4+rr, col(j_local) = r16  [m89-verified]
    #pragma unroll
    for (int g = 0; g < 4; ++g)
      #pragma unroll
      for (int rr = 0; rr < 4; ++rr)
        gacc[wv][g][kq*4 + rr][r16] = acc[g][rr];
    __syncthreads();

    float iv = 0.f, fv = 0.f, gv = 0.f, ov = 0.f;
    #pragma unroll
    for (int u = 0; u < 4; ++u) {
      iv += gacc[u][0][pb][pj];
      fv += gacc[u][1][pb][pj];
      gv += gacc[u][2][pb][pj];
      ov += gacc[u][3][pb][pj];
    }
    float ig = sigm(iv), fg = sigm(fv), gg = tanh_f(gv), og = sigm(ov);
    c_state = fg*c_state + ig*gg;
    float h = og * tanh_f(c_state);

    // pack 2 bf16 -> u32 via lane^1 exchange, store write-through to IF
    float hpart = __shfl_xor(h, 1, 64);
    if ((pj & 1) == 0) {
      u32 pk = (u32)f2bf(h) | ((u32)f2bf(hpart) << 16);
      size_t idx = (((size_t)d*TT + t)*BB + btb + pb)*128 + hs*8 + (pj >> 1);
      __hip_atomic_store(&Hst32[idx], pk, __ATOMIC_RELAXED, __HIP_MEMORY_SCOPE_AGENT);
    }
    asm volatile("s_waitcnt vmcnt(0)" ::: "memory");  // my stores are in the IF
    __syncthreads();                                  // everyone's stores are in the IF
    if (tid == 0)
      __hip_atomic_store(&flags[((size_t)((d*TT + t)*8 + bt))*64 + hs*4], 1u,
                         __ATOMIC_RELAXED, __HIP_MEMORY_SCOPE_AGENT);
  }
}

// ---------------- linear (512->128) + ELU ----------------
// grid 512 (one t per WG); feats = [H_fwd | H_bwd] read straight from Hst.
__global__ __launch_bounds__(256) void linear_elu(
    const u16* __restrict__ Hst, const u16* __restrict__ Wlin_pk,
    const float* __restrict__ blin, u16* __restrict__ feats2)
{
  const int t = blockIdx.x;
  const int tid = threadIdx.x;
  const int wv = tid >> 6, lane = tid & 63;
  const int r16 = lane & 15, kq = lane >> 4;
  __shared__ u16 w1s[32*512];   // 32KB quarter of W1, XOR-swizzled rows

  f32x4 acc[2][8];
  #pragma unroll
  for (int mi = 0; mi < 2; ++mi)
    #pragma unroll
    for (int nt = 0; nt < 8; ++nt) {
      float bv = blin[nt*16 + r16];
      acc[mi][nt] = (f32x4){bv,bv,bv,bv};
    }

  #pragma unroll
  for (int q = 0; q < 4; ++q) {
    __syncthreads();
    for (int i = tid; i < 2048; i += 256) {        // 32 rows x 64 chunks of 8 elems
      int rl = i >> 6, ch = i & 63;
      int dst = rl*1024 + ((ch*16) ^ ((rl & 7) << 4));
      *(bf16x8*)((char*)w1s + dst) = *(const bf16x8*)(Wlin_pk + (size_t)(q*32 + rl)*512 + ch*8);
    }
    __syncthreads();
    #pragma unroll
    for (int mi = 0; mi < 2; ++mi) {
      const int mb = (wv*2 + mi)*16;
      #pragma unroll
      for (int kc = 0; kc < 16; ++kc) {
        const int dd = kc >> 3, ki = kc & 7;
        const u16* ap = Hst + (((size_t)dd*TT + t)*BB + mb + r16)*256 + ki*32 + kq*8;
        bf16x8 a = *(const bf16x8*)ap;
        #pragma unroll
        for (int ntl = 0; ntl < 2; ++ntl) {
          int rl = ntl*16 + r16;
          int boff = kc*64 + kq*16;
          const u16* bp = (const u16*)((const char*)w1s + rl*1024 + (boff ^ ((rl & 7) << 4)));
          acc[mi][q*2 + ntl] = MFMA_B16(a, *(const bf16x8*)bp, acc[mi][q*2 + ntl]);
        }
      }
    }
  }
  // epilogue: ELU, pack 4 consecutive b, store feats2[t][n][b]
  #pragma unroll
  for (int mi = 0; mi < 2; ++mi) {
    const int mb = (wv*2 + mi)*16;
    #pragma unroll
    for (int nt = 0; nt < 8; ++nt) {
      u16x4 pk;
      #pragma unroll
      for (int rr = 0; rr < 4; ++rr) {
        float y = acc[mi][nt][rr];
        y = (y > 0.f) ? y : (__expf(y) - 1.f);
        pk[rr] = f2bf(y);
      }
      int n = nt*16 + r16;
      int bcol = mb + kq*4;
      *(u16x4*)(feats2 + ((size_t)t*128 + n)*BB + bcol) = pk;
    }
  }
}

// ---------------- classifier (128 -> 9) ----------------
__global__ __launch_bounds__(256) void cls_kernel(
    const u16* __restrict__ feats2, const float* __restrict__ Wcls,
    const float* __restrict__ bcls, float* __restrict__ em)
{
  __shared__ float w2s[9*128];
  __shared__ float b2s[9];
  const int tid = threadIdx.x;
  for (int i = tid; i < 9*128; i += 256) w2s[i] = Wcls[i];
  if (tid < 9) b2s[tid] = bcls[tid];
  __syncthreads();
  const int bb = tid & 127;
  const int t = blockIdx.x*2 + (tid >> 7);
  float accv[9];
  #pragma unroll
  for (int j = 0; j < 9; ++j) accv[j] = b2s[j];
  for (int n = 0; n < 128; ++n) {
    float y = bf2f(feats2[((size_t)t*128 + n)*BB + bb]);
    #pragma unroll
    for (int j = 0; j < 9; ++j) accv[j] = fmaf(w2s[j*128 + n], y, accv[j]);
  }
  #pragma unroll
  for (int j = 0; j < 9; ++j) em[((size_t)bb*TT + t)*9 + j] = accv[j];
}

// ---------------- CRF NLL per batch element ----------------
__global__ __launch_bounds__(64) void crf_kernel(
    const float* __restrict__ em, const int* __restrict__ labels,
    const float* __restrict__ start_t, const float* __restrict__ end_t,
    const float* __restrict__ trans, float* __restrict__ vals)
{
  const int b = blockIdx.x;
  const int lane = threadIdx.x;
  __shared__ float tr_s[81];
  for (int i = lane; i < 81; i += 64) tr_s[i] = trans[i];
  __syncthreads();
  const int* lb = labels + (size_t)b*TT;
  const float* emb = em + (size_t)b*TT*9;

  // numerator (mask is all ones, seq_len == T)
  float nsum = 0.f;
  for (int t = lane; t < TT; t += 64) {
    int lt = lb[t];
    float v = emb[t*9 + lt];
    v += (t == 0) ? start_t[lt] : tr_s[lb[t-1]*9 + lt];
    nsum += v;
  }
  #pragma unroll
  for (int o = 32; o > 0; o >>= 1) nsum += __shfl_down(nsum, o, 64);

  // forward algorithm; alpha replicated across lanes via shfl
  float tr_reg[9];
  #pragma unroll
  for (int i = 0; i < 9; ++i) tr_reg[i] = 0.f;
  if (lane < 9) {
    #pragma unroll
    for (int i = 0; i < 9; ++i) tr_reg[i] = tr_s[i*9 + lane];
  }
  float alpha_j = (lane < 9) ? (start_t[lane] + emb[lane]) : -1e30f;
  float a_all[9];
  #pragma unroll
  for (int i = 0; i < 9; ++i) a_all[i] = __shfl(alpha_j, i, 64);
  float em_c = (lane < 9) ? emb[9 + lane] : 0.f;
  for (int t = 1; t < TT; ++t) {
    float em_n = 0.f;
    if (t + 1 < TT && lane < 9) em_n = emb[(t+1)*9 + lane];   // prefetch
    float av[9];
    #pragma unroll
    for (int i = 0; i < 9; ++i) av[i] = a_all[i] + tr_reg[i];
    float m = av[0];
    #pragma unroll
    for (int i = 1; i < 9; ++i) m = fmaxf(m, av[i]);
    float ssum = 0.f;
    #pragma unroll
    for (int i = 0; i < 9; ++i) ssum += __expf(av[i] - m);
    float nxt = m + __logf(ssum) + em_c;
    #pragma unroll
    for (int i = 0; i < 9; ++i) a_all[i] = __shfl(nxt, i, 64);
    em_c = em_n;
  }
  if (lane == 0) {
    float vv[9];
    #pragma unroll
    for (int i = 0; i < 9; ++i) vv[i] = a_all[i] + end_t[i];
    float m = vv[0];
    #pragma unroll
    for (int i = 1; i < 9; ++i) m = fmaxf(m, vv[i]);
    float ssum = 0.f;
    #pragma unroll
    for (int i = 0; i < 9; ++i) ssum += __expf(vv[i] - m);
    float logZ = m + __logf(ssum);
    float num = nsum + end_t[lb[TT-1]];
    vals[b] = num - logZ;
  }
}

__global__ __launch_bounds__(128) void finalize_k(const float* __restrict__ vals, float* __restrict__ out){
  const int tid = threadIdx.x;
  float v = vals[tid];
  #pragma unroll
  for (int o = 32; o > 0; o >>= 1) v += __shfl_down(v, o, 64);
  __shared__ float sr[2];
  if ((tid & 63) == 0) sr[tid >> 6] = v;
  __syncthreads();
  if (tid == 0) out[0] = -(sr[0] + sr[1]);
}

// ---------------- launcher ----------------
extern "C" void kernel_launch(void* const* d_in, const int* in_sizes, int n_in,
                              void* d_out, int out_size, void* d_ws, size_t ws_size,
                              hipStream_t stream)
{
  const float* x       = (const float*)d_in[0];
  const int*   labels  = (const int*)d_in[2];
  const float* Wih_f   = (const float*)d_in[4];
  const float* Whh_f   = (const float*)d_in[5];
  const float* b_f     = (const float*)d_in[6];
  const float* Wih_b   = (const float*)d_in[7];
  const float* Whh_b   = (const float*)d_in[8];
  const float* b_b     = (const float*)d_in[9];
  const float* Wlin    = (const float*)d_in[10];
  const float* blin    = (const float*)d_in[11];
  const float* Wcls    = (const float*)d_in[12];
  const float* bcls    = (const float*)d_in[13];
  const float* start_t = (const float*)d_in[14];
  const float* end_t   = (const float*)d_in[15];
  const float* trans   = (const float*)d_in[16];

  char* p = (char*)d_ws;
  u16* xT     = (u16*)p;  p += (size_t)TT*BB*128*2;        // 16.78 MB
  u16* WhhP   = (u16*)p;  p += (size_t)2*1024*256*2;       //  1.05 MB
  u16* WihP   = (u16*)p;  p += (size_t)2*1024*128*2;       //  0.52 MB
  u16* WlinP  = (u16*)p;  p += (size_t)128*512*2;          //  0.13 MB
  u32* Hst32  = (u32*)p;  p += (size_t)2*TT*BB*128*4;      // 67.1 MB
  u16* feats2 = (u16*)p;  p += (size_t)TT*128*BB*2;        // 16.78 MB
  float* em   = (float*)p; p += (size_t)BB*TT*9*4;         //  2.36 MB
  u32* flags  = (u32*)p;  p += (size_t)2*TT*8*64*4;        //  2.10 MB
  float* vals = (float*)p; p += 128*4;

  hipMemsetAsync(flags, 0, (size_t)2*TT*8*64*4, stream);
  pack_x   <<<32768, 256, 0, stream>>>(x, xT);
  pack_whh <<<2048,  256, 0, stream>>>(Whh_f, Whh_b, WhhP);
  pack_wih <<<1024,  256, 0, stream>>>(Wih_f, Wih_b, WihP);
  pack_wlin<<<256,   256, 0, stream>>>(Wlin, WlinP);
  lstm_scan<<<256,   256, 0, stream>>>(xT, WhhP, WihP, b_f, b_b, Hst32, flags);
  linear_elu<<<512,  256, 0, stream>>>((const u16*)Hst32, WlinP, blin, feats2);
  cls_kernel<<<256,  256, 0, stream>>>(feats2, Wcls, bcls, em);
  crf_kernel<<<128,  64,  0, stream>>>(em, labels, start_t, end_t, trans, vals);
  finalize_k<<<1,    128, 0, stream>>>(vals, (float*)d_out);
}